// Round 21
// baseline (169.092 us; speedup 1.0000x reference)
//
#include <hip/hip_runtime.h>
#include <stdint.h>

// B=4, C=256, H=W=64, N=4096, CQK=16, Ktot=C*9=2304
// ws layout:
//   qT  [4][4096][64] bf16   @ 0     (2 MiB)
//   kT  [4][4096][32] bf16   @ 2 MiB (1 MiB)
//   VF  [4][128][16][512] bf16 @ 3 MiB (8 MiB) V in MFMA-fragment order
//   W3v [4][18][256][32] bf16 @ 11 MiB (1152 KiB)
//   W3q [4][18][16][32]  bf16 @ +1179648 (72 KiB)
//   W3k [4][18][16][32]  bf16 @ +73728   (72 KiB)
//   yF  [4][64][4][2][66][32] bf16 @ 13 MiB (8.25 MiB)  y fragment-major; wH 0/65 zero halo

typedef __bf16 bf16;
typedef bf16 bf16x8 __attribute__((ext_vector_type(8)));
typedef float f32x4 __attribute__((ext_vector_type(4)));
typedef unsigned long long ull;

#define DEV static __device__ __forceinline__

DEV f32x4 mfma16(bf16x8 a, bf16x8 b, f32x4 c) {
  return __builtin_amdgcn_mfma_f32_16x16x32_bf16(a, b, c, 0, 0, 0);
}

#define SMBUF 25344   // conv_qk staging buffer (3*66*64*2B)
#define YSLAB 4224    // one (kh,half) yF slab: 66 rows x 64B

// ===================== weight pack (all 3 tensors, one launch) =====================
__global__ void pack_all_kernel(const float* __restrict__ wv, const float* __restrict__ wq,
                                const float* __restrict__ wk, bf16* __restrict__ W3v,
                                bf16* __restrict__ W3q, bf16* __restrict__ W3k) {
  int idx = blockIdx.x * 256 + threadIdx.x;
  if (idx >= 663552) return;
  const float* src;
  bf16* dst;
  int rel, O;
  if (idx < 589824)      { src = wv; dst = W3v; rel = idx; O = 256; }
  else if (idx < 626688) { src = wq; dst = W3q; rel = idx - 589824; O = 16; }
  else                   { src = wk; dst = W3k; rel = idx - 626688; O = 16; }
  int o = rel / 2304, r = rel - o * 2304;
  int ci = r / 9, tap = r - ci * 9;
  int chunk = ci >> 6, c6 = ci & 63;
  int ks = (tap << 1) + (c6 >> 5), j = c6 & 31;
  dst[((chunk * 18 + ks) * O + o) * 32 + j] = (bf16)src[rel];
}

// ===================== yF pre-pass: y -> bf16 fragment-major =====================
__global__ __launch_bounds__(256) void pack_yF_kernel(
    const float* __restrict__ y, bf16* __restrict__ yF) {
  __shared__ __align__(16) char sm[66 * 128];
  const int t = threadIdx.x;
  const int raw = blockIdx.x;
  const int b = raw >> 8, h = (raw >> 2) & 63, chunk = raw & 3;
  const int wg = t & 15, clq = t >> 4;
  float4 xv[4];
#pragma unroll
  for (int cc = 0; cc < 4; ++cc)
    xv[cc] = *(const float4*)&y[((((size_t)b << 8) + (chunk << 6) + (clq << 2) + cc) * 64 + h) * 64 + (wg << 2)];
  const float xs0[4] = {xv[0].x, xv[0].y, xv[0].z, xv[0].w};
  const float xs1[4] = {xv[1].x, xv[1].y, xv[1].z, xv[1].w};
  const float xs2[4] = {xv[2].x, xv[2].y, xv[2].z, xv[2].w};
  const float xs3[4] = {xv[3].x, xv[3].y, xv[3].z, xv[3].w};
#pragma unroll
  for (int q4 = 0; q4 < 4; ++q4) {
    int wH = (wg << 2) + q4 + 1;
    union { bf16 h4[4]; ull v; } pk;
    pk.h4[0] = (bf16)xs0[q4]; pk.h4[1] = (bf16)xs1[q4];
    pk.h4[2] = (bf16)xs2[q4]; pk.h4[3] = (bf16)xs3[q4];
    *(ull*)(sm + (((wH << 7) + (clq << 3)) ^ ((wH & 7) << 4))) = pk.v;
  }
  __syncthreads();
  ull* dst = (ull*)yF + (size_t)(((b * 64 + h) * 4 + chunk) * 2) * 66 * 8;
  for (int idx = t; idx < 1056; idx += 256) {
    int half = (idx >= 528) ? 1 : 0;
    int rem = idx - half * 528;
    int wH = rem >> 3, gr = rem & 7;
    ull v = 0;
    if (wH != 0 && wH != 65)
      v = *(const ull*)(sm + (((wH << 7) + (half << 6) + (gr << 3)) ^ ((wH & 7) << 4)));
    dst[(size_t)(half * 66 + wH) * 8 + gr] = v;
  }
}

// ===================== conv staging (for conv_qk only) ==========
DEV void stage_load(float4* xv, const float* __restrict__ img, int b, int h, int ci0, int t) {
  const int wg = t & 15, clq = t >> 4;
#pragma unroll
  for (int dh = 0; dh < 3; ++dh) {
    int hh = h + dh - 1;
    bool ok = (hh >= 0) && (hh < 64);
#pragma unroll
    for (int cc = 0; cc < 4; ++cc) {
      float4 v = make_float4(0.f, 0.f, 0.f, 0.f);
      if (ok) v = *(const float4*)&img[((((size_t)b << 8) + ci0 + (clq << 2) + cc) * 64 + hh) * 64 + (wg << 2)];
      xv[dh * 4 + cc] = v;
    }
  }
}

DEV void stage_write(char* smc, const float4* xv, int t) {
  if (t < 96) {
    int dh = t >> 5, r = t & 31;
    int wH = (r & 16) ? 65 : 0, cq = r & 15;
    *(ull*)(smc + ((((dh * 66 + wH) << 7) + (cq << 3)) ^ ((wH & 7) << 4))) = 0ull;
  }
  const int wg = t & 15, clq = t >> 4;
#pragma unroll
  for (int dh = 0; dh < 3; ++dh) {
    const float4 a = xv[dh * 4 + 0], b4 = xv[dh * 4 + 1], c4 = xv[dh * 4 + 2], d4 = xv[dh * 4 + 3];
    const float ax[4] = {a.x, a.y, a.z, a.w};
    const float bx[4] = {b4.x, b4.y, b4.z, b4.w};
    const float cx[4] = {c4.x, c4.y, c4.z, c4.w};
    const float dx[4] = {d4.x, d4.y, d4.z, d4.w};
#pragma unroll
    for (int q4 = 0; q4 < 4; ++q4) {
      int wH = (wg << 2) + q4 + 1;
      union { bf16 h4[4]; ull v; } pk;
      pk.h4[0] = (bf16)ax[q4]; pk.h4[1] = (bf16)bx[q4];
      pk.h4[2] = (bf16)cx[q4]; pk.h4[3] = (bf16)dx[q4];
      *(ull*)(smc + ((((dh * 66 + wH) << 7) + (clq << 3)) ^ ((wH & 7) << 4))) = pk.v;
    }
  }
}

// ===================== conv q + k fused (O=16), pipelined staging =====================
__global__ __launch_bounds__(256) void conv_qk_kernel(
    const float* __restrict__ x, const float* __restrict__ y,
    const bf16* __restrict__ W3q, const bf16* __restrict__ W3k,
    const float* __restrict__ bq, const float* __restrict__ bk,
    bf16* __restrict__ qT, bf16* __restrict__ kT) {
  __shared__ __align__(16) char smc[2 * SMBUF];
  const int mode = blockIdx.x >> 8;       // 0=q, 1=k
  const float* img = mode ? y : x;
  const bf16* W3 = mode ? W3k : W3q;
  const float* bias = mode ? bk : bq;
  const int bi = blockIdx.x & 255;
  const int t = threadIdx.x;
  const int lane = t & 63, wv = t >> 6;
  const int g = lane >> 4, ln = lane & 15;
  const int b = bi >> 6;
  const int h = bi & 63;
  f32x4 acc = {0.f, 0.f, 0.f, 0.f};
  float4 xv[12];
  stage_load(xv, img, b, h, 0, t);
  stage_write(smc, xv, t);
  __syncthreads();
  for (int chunk = 0; chunk < 4; ++chunk) {
    char* cur = smc + (chunk & 1) * SMBUF;
    if (chunk < 3) stage_load(xv, img, b, h, (chunk + 1) << 6, t);
#pragma unroll
    for (int ks = 0; ks < 18; ++ks) {
      const int tap = ks >> 1, clb = (ks & 1) << 5;
      const int kh = tap / 3, kw = tap - kh * 3;
      const int wH = (wv << 4) + ln + kw;
      uint32_t bo = ((((kh * 66 + wH) << 6) + clb + (g << 3)) << 1) ^ ((wH & 7) << 4);
      bf16x8 bfr = *(const bf16x8*)(cur + bo);
      bf16x8 afr = *(const bf16x8*)&W3[(size_t)((chunk * 18 + ks) * 16 + ln) * 32 + (g << 3)];
      acc = mfma16(afr, bfr, acc);
    }
    if (chunk < 3) stage_write(smc + ((chunk + 1) & 1) * SMBUF, xv, t);
    __syncthreads();
  }
  const int p = (h << 6) + (wv << 4) + ln;
#pragma unroll
  for (int r = 0; r < 4; ++r) {
    int o = (g << 2) + r;
    float val = acc[r] + bias[o];
    if (mode == 0) {
      val *= 1.4426950408889634f;              // log2(e): softmax via exp2
      bf16* drow = qT + (((size_t)b << 12) + p) * 64;
      bf16 hi = (bf16)val;
      drow[o] = hi;
      drow[16 + o] = hi;                       // B1 = [qh|qh]
      drow[32 + o] = (bf16)(val - (float)hi);  // B2 = [ql|0]
      drow[48 + o] = (bf16)0.f;
    } else {
      bf16* drow = kT + (((size_t)b << 12) + p) * 32;
      bf16 hi = (bf16)val;
      drow[o] = hi;                            // A = [kh|kl]
      drow[16 + o] = (bf16)(val - (float)hi);
    }
  }
}

// ===================== conv v v4: waves split PIXELS, weights from L1 ===============
// r20 PMC: conv_v LDS-pipe-bound — all 4 waves read the IDENTICAL bfr stream (waves
// split o), 1152 b128 LDS reads/block + 4.7M conflict cyc. Fix: wave wv owns pixel
// quarter wf=wv -> ONE bfr per ks per wave (288 LDS reads/block, 4x less); all 4 o-block
// afr come from W3 global (1KB coalesced; 4 waves in near-lockstep -> L1-hot, shared
// across all h-blocks via L2). MFMA:LDS-read 1:1 -> 4:1. acc[4] (ob). grid 1024.
__global__ __launch_bounds__(256) void conv_v_kernel(
    const bf16* __restrict__ yF, const bf16* __restrict__ W3,
    const float* __restrict__ bias, bf16* __restrict__ VF) {
  __shared__ __align__(16) char smc[6 * YSLAB];   // [kh 3][half 2][wH 66][64B] linear
  const int t = threadIdx.x;
  const int lane = t & 63, wv = t >> 6;
  const int g = lane >> 4, ln = lane & 15;
  const int raw = blockIdx.x;          // 1024 = b(4) x h(64) x oh(4)
  const int b = raw >> 8;
  const int h = (raw >> 2) & 63;
  const int oh = raw & 3;
  const int obase = oh << 6;           // block covers 64 o; wave covers pixel quarter wv
  const int wf16 = wv << 4;
  const int kh0 = (h == 0) ? 1 : 0, kh1 = (h == 63) ? 2 : 3;   // valid kh range
  f32x4 acc[4];                         // [ob]
#pragma unroll
  for (int ob = 0; ob < 4; ++ob) acc[ob] = (f32x4){0.f, 0.f, 0.f, 0.f};

  f32x4 xmain[6];
  f32x4 xtail[6];
#define YBASE(kh, half, chunk) ((const char*)yF + \
    (size_t)((((b * 64 + (h + (kh) - 1)) * 4 + (chunk)) * 2 + (half)) * YSLAB))

#define LOADC(chunk)                                                       \
  {                                                                        \
    _Pragma("unroll")                                                      \
    for (int kh = 0; kh < 3; ++kh)                                         \
      if (kh >= kh0 && kh < kh1)                                           \
        _Pragma("unroll")                                                  \
        for (int half = 0; half < 2; ++half) {                             \
          const char* src = YBASE(kh, half, chunk);                        \
          xmain[kh * 2 + half] = *(const f32x4*)(src + (t << 4));          \
          if (t < 8) xtail[kh * 2 + half] = *(const f32x4*)(src + 4096 + (t << 4)); \
        }                                                                  \
  }

#define WRITEC()                                                           \
  {                                                                        \
    _Pragma("unroll")                                                      \
    for (int kh = 0; kh < 3; ++kh)                                         \
      if (kh >= kh0 && kh < kh1)                                           \
        _Pragma("unroll")                                                  \
        for (int half = 0; half < 2; ++half) {                             \
          char* dst = smc + (kh * 2 + half) * YSLAB;                       \
          *(f32x4*)(dst + (t << 4)) = xmain[kh * 2 + half];                \
          if (t < 8) *(f32x4*)(dst + 4096 + (t << 4)) = xtail[kh * 2 + half]; \
        }                                                                  \
  }

  LOADC(0)
  WRITEC()
  __syncthreads();
  for (int chunk = 0; chunk < 4; ++chunk) {
    if (chunk < 3) LOADC(chunk + 1)   // next-chunk loads fly under the MFMA phase
#pragma unroll
    for (int kh = 0; kh < 3; ++kh) {
      if (kh < kh0 || kh >= kh1) continue;   // uniform skip (h==0 / h==63 edges)
#pragma unroll
      for (int kw = 0; kw < 3; ++kw) {
#pragma unroll
        for (int half = 0; half < 2; ++half) {
          const int ks = ((kh * 3 + kw) << 1) + half;
          // one bfr per wave: its own 16-pixel window (row = wf*16+ln+kw)
          bf16x8 bfr = *(const bf16x8*)(smc + (kh * 2 + half) * YSLAB +
                                        ((wf16 + ln + kw) << 6) + (g << 4));
          const bf16* wrow = &W3[(size_t)((chunk * 18 + ks) * 256 + obase + ln) * 32 + (g << 3)];
#pragma unroll
          for (int ob = 0; ob < 4; ++ob) {
            bf16x8 afr = *(const bf16x8*)(wrow + (size_t)(ob << 4) * 32);  // o = obase+ob*16+ln
            acc[ob] = mfma16(afr, bfr, acc[ob]);
          }
        }
      }
    }
    if (chunk < 3) {
      __syncthreads();   // readers done with this chunk
      WRITEC()
      __syncthreads();   // staging visible
    }
  }
#undef YBASE
#undef LOADC
#undef WRITEC
  // epilogue -> VF[b][J][cblk][g][ln][e]; o = obase+ob*16+g*4+r, p = h*64+wf*16+ln
  const int p = (h << 6) + wf16 + ln;
  const int J = p >> 5, gv = (p >> 3) & 3, e = p & 7;
#pragma unroll
  for (int ob = 0; ob < 4; ++ob) {
    const int cblk = (oh << 2) + ob;
#pragma unroll
    for (int r = 0; r < 4; ++r) {
      int c = obase + (ob << 4) + (g << 2) + r;
      int lnv = c & 15;
      VF[(((size_t)(((b << 7) + J) << 4) + cblk) << 9) + (gv << 7) + (lnv << 3) + e] =
          (bf16)(acc[ob][r] + bias[c]);
    }
  }
}

// ===================== attention =====================
// Proven structure (~45-55 µs): producer/consumer, __syncthreads dbuf,
// launch_bounds(512,2), VF fragment-ordered V -> 1KB coalesced av loads.
__global__ __launch_bounds__(512, 2) void attn_kernel(
    const bf16* __restrict__ qT, const bf16* __restrict__ kT,
    const bf16* __restrict__ VF, float* __restrict__ outp) {
  __shared__ __align__(16) char Klds[2 * 4096];   // [buf][row 64][64B] swizzled
  __shared__ __align__(16) char Plds[2 * 8192];   // [buf][f 4][ln 16][128B] swizzled
  __shared__ float lsumS[4][16];
  const int raw = blockIdx.x;          // 256
  const int b  = raw & 3;              // batch -> XCD pair {b, b+4}
  const int it = raw >> 2;             // 0..63
  const int i0 = it << 6;
  const int t = threadIdx.x;
  const int lane = t & 63, wv = t >> 6;
  const int g = lane >> 4, ln = lane & 15;
  const bool prod = (wv < 4);
  const int f = wv & 3;
  const int cb = f << 6;
  const int cblk0 = f << 2;

  const char* kTb = (const char*)kT + (((size_t)b << 12) << 6);
  const char* vfb = (const char*)VF + ((size_t)b << 21);

  bf16x8 bq1 = {}, bq2 = {};
  if (prod) {
    const bf16* qrow = &qT[(((size_t)b << 12) + i0 + (f << 4) + ln) * 64];
    bq1 = *(const bf16x8*)&qrow[g << 3];
    bq2 = *(const bf16x8*)&qrow[32 + (g << 3)];
  }
  float lsum = 0.f;
  const int krow = t >> 2, kc = t & 3;
  const uint32_t kwoff = ((uint32_t)krow << 6) + ((uint32_t)(kc ^ (krow & 3)) << 4);

  f32x4 acc[4][4];
#pragma unroll
  for (int cf = 0; cf < 4; ++cf)
#pragma unroll
    for (int ff = 0; ff < 4; ++ff) acc[cf][ff] = (f32x4){0.f, 0.f, 0.f, 0.f};
  bf16x8 avA[8], avB[8];

  if (prod)
    *(f32x4*)(Klds + kwoff) = *(const f32x4*)(kTb + ((size_t)krow << 6) + (kc << 4));
  __syncthreads();

  for (int m = 0; m < 32; ++m) {
    const int jtA = m << 1;
    if (prod) {
      f32x4 s[4];
#pragma unroll
      for (int jf = 0; jf < 4; ++jf) {
        const int row = (jf << 4) + ln;
        bf16x8 ak = *(const bf16x8*)(Klds + ((uint32_t)row << 6) + ((uint32_t)(g ^ (row & 3)) << 4));
        f32x4 z = {0.f, 0.f, 0.f, 0.f};
        s[jf] = mfma16(ak, bq2, mfma16(ak, bq1, z));
      }
#pragma unroll
      for (int jf = 0; jf < 4; ++jf) {
        union { bf16 h[4]; ull v; } pk;
#pragma unroll
        for (int r = 0; r < 4; ++r) {
          float pv = __builtin_amdgcn_exp2f(s[jf][r]);
          lsum += pv;
          pk.h[r] = (bf16)pv;
        }
        uint32_t bo = (((uint32_t)f << 11) + ((uint32_t)ln << 7) + (jf << 5) + (g << 3)) ^ ((ln & 7) << 4);
        *(ull*)(Plds + bo) = pk.v;
      }
      *(f32x4*)(Klds + 4096 + kwoff) =
          *(const f32x4*)(kTb + ((size_t)(((jtA + 1) << 6) + krow) << 6) + (kc << 4));
    } else {
#pragma unroll
      for (int ks = 0; ks < 2; ++ks)
#pragma unroll
        for (int cf = 0; cf < 4; ++cf)
          avB[ks * 4 + cf] = *(const bf16x8*)(vfb +
              ((size_t)(((jtA << 1) + ks) * 16 + cblk0 + cf) << 10) + (lane << 4));
      if (m > 0) {
        __builtin_amdgcn_s_setprio(1);
#pragma unroll
        for (int ks = 0; ks < 2; ++ks) {
          bf16x8 bp[4];
#pragma unroll
          for (int ff = 0; ff < 4; ++ff) {
            uint32_t bo = (8192u + ((uint32_t)ff << 11) + ((uint32_t)ln << 7) + (ks << 6) + (g << 4)) ^ ((ln & 7) << 4);
            bp[ff] = *(const bf16x8*)(Plds + bo);
          }
#pragma unroll
          for (int cf = 0; cf < 4; ++cf)
#pragma unroll
            for (int ff = 0; ff < 4; ++ff)
              acc[cf][ff] = mfma16(avA[ks * 4 + cf], bp[ff], acc[cf][ff]);
        }
        __builtin_amdgcn_s_setprio(0);
      }
    }
    __syncthreads();
    const int jtB = jtA + 1;
    if (prod) {
      f32x4 s[4];
#pragma unroll
      for (int jf = 0; jf < 4; ++jf) {
        const int row = (jf << 4) + ln;
        bf16x8 ak = *(const bf16x8*)(Klds + 4096 + ((uint32_t)row << 6) + ((uint32_t)(g ^ (row & 3)) << 4));
        f32x4 z = {0.f, 0.f, 0.f, 0.f};
        s[jf] = mfma16(ak, bq2, mfma16(ak, bq1, z));
      }
#pragma unroll
      for (int jf = 0; jf < 4; ++jf) {
        union { bf16 h[4]; ull v; } pk;
#pragma unroll
        for (int r = 0; r < 4; ++r) {
          float pv = __builtin_amdgcn_exp2f(s[jf][r]);
          lsum += pv;
          pk.h[r] = (bf16)pv;
        }
        uint32_t bo = (8192u + ((uint32_t)f << 11) + ((uint32_t)ln << 7) + (jf << 5) + (g << 3)) ^ ((ln & 7) << 4);
        *(ull*)(Plds + bo) = pk.v;
      }
      if (m < 31)
        *(f32x4*)(Klds + kwoff) =
            *(const f32x4*)(kTb + ((size_t)(((jtB + 1) << 6) + krow) << 6) + (kc << 4));
    } else {
#pragma unroll
      for (int ks = 0; ks < 2; ++ks)
#pragma unroll
        for (int cf = 0; cf < 4; ++cf)
          avA[ks * 4 + cf] = *(const bf16x8*)(vfb +
              ((size_t)(((jtB << 1) + ks) * 16 + cblk0 + cf) << 10) + (lane << 4));
      __builtin_amdgcn_s_setprio(1);
#pragma unroll
      for (int ks = 0; ks < 2; ++ks) {
        bf16x8 bp[4];
#pragma unroll
        for (int ff = 0; ff < 4; ++ff) {
          uint32_t bo = (((uint32_t)ff << 11) + ((uint32_t)ln << 7) + (ks << 6) + (g << 4)) ^ ((ln & 7) << 4);
          bp[ff] = *(const bf16x8*)(Plds + bo);
        }
#pragma unroll
        for (int cf = 0; cf < 4; ++cf)
#pragma unroll
          for (int ff = 0; ff < 4; ++ff)
            acc[cf][ff] = mfma16(avB[ks * 4 + cf], bp[ff], acc[cf][ff]);
      }
      __builtin_amdgcn_s_setprio(0);
    }
    __syncthreads();
  }
  if (prod) {
    float l = lsum;
    l += __shfl_xor(l, 16, 64);
    l += __shfl_xor(l, 32, 64);
    if (g == 0) lsumS[f][ln] = l;
  } else {
#pragma unroll
    for (int ks = 0; ks < 2; ++ks) {
      bf16x8 bp[4];
#pragma unroll
      for (int ff = 0; ff < 4; ++ff) {
        uint32_t bo = (8192u + ((uint32_t)ff << 11) + ((uint32_t)ln << 7) + (ks << 6) + (g << 4)) ^ ((ln & 7) << 4);
        bp[ff] = *(const bf16x8*)(Plds + bo);
      }
#pragma unroll
      for (int cf = 0; cf < 4; ++cf)
#pragma unroll
        for (int ff = 0; ff < 4; ++ff)
          acc[cf][ff] = mfma16(avA[ks * 4 + cf], bp[ff], acc[cf][ff]);
    }
  }
  __syncthreads();
  if (!prod) {
#pragma unroll
    for (int ff = 0; ff < 4; ++ff) {
      float rdiv = 1.f / lsumS[ff][ln];
      const int i = i0 + (ff << 4) + ln;
#pragma unroll
      for (int cf = 0; cf < 4; ++cf)
#pragma unroll
        for (int r = 0; r < 4; ++r) {
          int c = cb + (cf << 4) + (g << 2) + r;
          outp[(((size_t)b << 8) + c) * 4096 + i] = acc[cf][ff][r] * rdiv;
        }
    }
  }
}

// ===================== launch =====================
extern "C" void kernel_launch(void* const* d_in, const int* in_sizes, int n_in,
                              void* d_out, int out_size, void* d_ws, size_t ws_size,
                              hipStream_t stream) {
  const float* x  = (const float*)d_in[0];
  const float* y  = (const float*)d_in[1];
  const float* wq = (const float*)d_in[2];
  const float* bq = (const float*)d_in[3];
  const float* wk = (const float*)d_in[4];
  const float* bk = (const float*)d_in[5];
  const float* wv = (const float*)d_in[6];
  const float* bv = (const float*)d_in[7];
  float* out = (float*)d_out;

  char* ws = (char*)d_ws;
  bf16* qT  = (bf16*)(ws);
  bf16* kT  = (bf16*)(ws + (2u << 20));
  bf16* VF  = (bf16*)(ws + (3u << 20));
  bf16* W3v = (bf16*)(ws + (11u << 20));
  bf16* W3q = (bf16*)(ws + (11u << 20) + 1179648u);
  bf16* W3k = (bf16*)(ws + (11u << 20) + 1179648u + 73728u);
  bf16* yF  = (bf16*)(ws + (13u << 20));

  pack_all_kernel<<<2592, 256, 0, stream>>>(wv, wq, wk, W3v, W3q, W3k);
  pack_yF_kernel<<<1024, 256, 0, stream>>>(y, yF);
  conv_qk_kernel<<<512, 256, 0, stream>>>(x, y, W3q, W3k, bq, bk, qT, kT);
  conv_v_kernel<<<1024, 256, 0, stream>>>(yF, W3v, bv, VF);
  attn_kernel<<<256, 512, 0, stream>>>(qT, kT, VF, out);
}

// Round 22
// 129.291 us; speedup vs baseline: 1.3078x; 1.3078x over previous
//
#include <hip/hip_runtime.h>
#include <stdint.h>

// B=4, C=256, H=W=64, N=4096, CQK=16, Ktot=C*9=2304
// ws layout:
//   qT  [4][4096][64] bf16   @ 0     (2 MiB)
//   kT  [4][4096][32] bf16   @ 2 MiB (1 MiB)
//   VF  [4][128][16][512] bf16 @ 3 MiB (8 MiB) V in MFMA-fragment order
//   W3v [4][18][256][32] bf16 @ 11 MiB (1152 KiB)
//   W3q [4][18][16][32]  bf16 @ +1179648 (72 KiB)
//   W3k [4][18][16][32]  bf16 @ +73728   (72 KiB)
//   yF  [4][64][4][2][66][32] bf16 @ 13 MiB (8.25 MiB)  y fragment-major; wH 0/65 zero halo
//        (written by conv_qk k-mode during its staging — pack_yF kernel eliminated)

typedef __bf16 bf16;
typedef bf16 bf16x8 __attribute__((ext_vector_type(8)));
typedef float f32x4 __attribute__((ext_vector_type(4)));
typedef unsigned long long ull;

#define DEV static __device__ __forceinline__

DEV f32x4 mfma16(bf16x8 a, bf16x8 b, f32x4 c) {
  return __builtin_amdgcn_mfma_f32_16x16x32_bf16(a, b, c, 0, 0, 0);
}

#define SMBUF 25344   // conv_qk staging buffer (3*66*64*2B)
#define YSLAB 4224    // one (kh,half) yF slab: 66 rows x 64B

// ===================== weight pack (all 3 tensors, one launch) =====================
__global__ void pack_all_kernel(const float* __restrict__ wv, const float* __restrict__ wq,
                                const float* __restrict__ wk, bf16* __restrict__ W3v,
                                bf16* __restrict__ W3q, bf16* __restrict__ W3k) {
  int idx = blockIdx.x * 256 + threadIdx.x;
  if (idx >= 663552) return;
  const float* src;
  bf16* dst;
  int rel, O;
  if (idx < 589824)      { src = wv; dst = W3v; rel = idx; O = 256; }
  else if (idx < 626688) { src = wq; dst = W3q; rel = idx - 589824; O = 16; }
  else                   { src = wk; dst = W3k; rel = idx - 626688; O = 16; }
  int o = rel / 2304, r = rel - o * 2304;
  int ci = r / 9, tap = r - ci * 9;
  int chunk = ci >> 6, c6 = ci & 63;
  int ks = (tap << 1) + (c6 >> 5), j = c6 & 31;
  dst[((chunk * 18 + ks) * O + o) * 32 + j] = (bf16)src[rel];
}

// ===================== conv staging (split load/write) ==========
DEV void stage_load(float4* xv, const float* __restrict__ img, int b, int h, int ci0, int t) {
  const int wg = t & 15, clq = t >> 4;
#pragma unroll
  for (int dh = 0; dh < 3; ++dh) {
    int hh = h + dh - 1;
    bool ok = (hh >= 0) && (hh < 64);
#pragma unroll
    for (int cc = 0; cc < 4; ++cc) {
      float4 v = make_float4(0.f, 0.f, 0.f, 0.f);
      if (ok) v = *(const float4*)&img[((((size_t)b << 8) + ci0 + (clq << 2) + cc) * 64 + hh) * 64 + (wg << 2)];
      xv[dh * 4 + cc] = v;
    }
  }
}

DEV void stage_write(char* smc, const float4* xv, int t) {
  if (t < 96) {
    int dh = t >> 5, r = t & 31;
    int wH = (r & 16) ? 65 : 0, cq = r & 15;
    *(ull*)(smc + ((((dh * 66 + wH) << 7) + (cq << 3)) ^ ((wH & 7) << 4))) = 0ull;
  }
  const int wg = t & 15, clq = t >> 4;
#pragma unroll
  for (int dh = 0; dh < 3; ++dh) {
    const float4 a = xv[dh * 4 + 0], b4 = xv[dh * 4 + 1], c4 = xv[dh * 4 + 2], d4 = xv[dh * 4 + 3];
    const float ax[4] = {a.x, a.y, a.z, a.w};
    const float bx[4] = {b4.x, b4.y, b4.z, b4.w};
    const float cx[4] = {c4.x, c4.y, c4.z, c4.w};
    const float dx[4] = {d4.x, d4.y, d4.z, d4.w};
#pragma unroll
    for (int q4 = 0; q4 < 4; ++q4) {
      int wH = (wg << 2) + q4 + 1;
      union { bf16 h4[4]; ull v; } pk;
      pk.h4[0] = (bf16)ax[q4]; pk.h4[1] = (bf16)bx[q4];
      pk.h4[2] = (bf16)cx[q4]; pk.h4[3] = (bf16)dx[q4];
      *(ull*)(smc + ((((dh * 66 + wH) << 7) + (clq << 3)) ^ ((wH & 7) << 4))) = pk.v;
    }
  }
}

// yF write from conv_qk k-mode registers (dh=1 row of xv), replaces pack_yF kernel.
// Mapping desk-checked vs pack_yF: half=clq>>3, gr=clq&7, ci=chunk*64+clq*4+cc.
DEV void yF_write(bf16* __restrict__ yFo, const float4* xv, int b, int h, int chunk, int t) {
  const int wg = t & 15, clq = t >> 4;
  const int half = clq >> 3, gr = clq & 7;
  ull* base = (ull*)yFo + ((size_t)(((b * 64 + h) * 4 + chunk) * 2 + half) * 66) * 8 + gr;
  const float4 a = xv[4 + 0], b4 = xv[4 + 1], c4 = xv[4 + 2], d4 = xv[4 + 3];
  const float ax[4] = {a.x, a.y, a.z, a.w};
  const float bx[4] = {b4.x, b4.y, b4.z, b4.w};
  const float cx[4] = {c4.x, c4.y, c4.z, c4.w};
  const float dx[4] = {d4.x, d4.y, d4.z, d4.w};
#pragma unroll
  for (int q4 = 0; q4 < 4; ++q4) {
    int wH = (wg << 2) + q4 + 1;
    union { bf16 h4[4]; ull v; } pk;
    pk.h4[0] = (bf16)ax[q4]; pk.h4[1] = (bf16)bx[q4];
    pk.h4[2] = (bf16)cx[q4]; pk.h4[3] = (bf16)dx[q4];
    base[(size_t)wH * 8] = pk.v;
  }
}

// ===================== conv q + k fused (O=16), pipelined staging; k-mode emits yF ====
__global__ __launch_bounds__(256) void conv_qk_kernel(
    const float* __restrict__ x, const float* __restrict__ y,
    const bf16* __restrict__ W3q, const bf16* __restrict__ W3k,
    const float* __restrict__ bq, const float* __restrict__ bk,
    bf16* __restrict__ qT, bf16* __restrict__ kT, bf16* __restrict__ yFo) {
  __shared__ __align__(16) char smc[2 * SMBUF];
  const int mode = blockIdx.x >> 8;       // 0=q, 1=k
  const float* img = mode ? y : x;
  const bf16* W3 = mode ? W3k : W3q;
  const float* bias = mode ? bk : bq;
  const int bi = blockIdx.x & 255;
  const int t = threadIdx.x;
  const int lane = t & 63, wv = t >> 6;
  const int g = lane >> 4, ln = lane & 15;
  const int b = bi >> 6;
  const int h = bi & 63;
  f32x4 acc = {0.f, 0.f, 0.f, 0.f};
  float4 xv[12];
  stage_load(xv, img, b, h, 0, t);
  if (mode) {
    // one-time halo zeroing for this (b,h): 4 chunks x 2 half x {wH=0,65} x 8 ull
    if (t < 128) {
      int chunk = t >> 5, half = (t >> 4) & 1, wside = (t >> 3) & 1, gr = t & 7;
      int wH = wside ? 65 : 0;
      ((ull*)yFo)[((size_t)(((b * 64 + h) * 4 + chunk) * 2 + half) * 66 + wH) * 8 + gr] = 0ull;
    }
    yF_write(yFo, xv, b, h, 0, t);
  }
  stage_write(smc, xv, t);
  __syncthreads();
  for (int chunk = 0; chunk < 4; ++chunk) {
    char* cur = smc + (chunk & 1) * SMBUF;
    if (chunk < 3) {
      stage_load(xv, img, b, h, (chunk + 1) << 6, t);
      if (mode) yF_write(yFo, xv, b, h, chunk + 1, t);
    }
#pragma unroll
    for (int ks = 0; ks < 18; ++ks) {
      const int tap = ks >> 1, clb = (ks & 1) << 5;
      const int kh = tap / 3, kw = tap - kh * 3;
      const int wH = (wv << 4) + ln + kw;
      uint32_t bo = ((((kh * 66 + wH) << 6) + clb + (g << 3)) << 1) ^ ((wH & 7) << 4);
      bf16x8 bfr = *(const bf16x8*)(cur + bo);
      bf16x8 afr = *(const bf16x8*)&W3[(size_t)((chunk * 18 + ks) * 16 + ln) * 32 + (g << 3)];
      acc = mfma16(afr, bfr, acc);
    }
    if (chunk < 3) stage_write(smc + ((chunk + 1) & 1) * SMBUF, xv, t);
    __syncthreads();
  }
  const int p = (h << 6) + (wv << 4) + ln;
#pragma unroll
  for (int r = 0; r < 4; ++r) {
    int o = (g << 2) + r;
    float val = acc[r] + bias[o];
    if (mode == 0) {
      val *= 1.4426950408889634f;              // log2(e): softmax via exp2
      bf16* drow = qT + (((size_t)b << 12) + p) * 64;
      bf16 hi = (bf16)val;
      drow[o] = hi;
      drow[16 + o] = hi;                       // B1 = [qh|qh]
      drow[32 + o] = (bf16)(val - (float)hi);  // B2 = [ql|0]
      drow[48 + o] = (bf16)0.f;
    } else {
      bf16* drow = kT + (((size_t)b << 12) + p) * 32;
      bf16 hi = (bf16)val;
      drow[o] = hi;                            // A = [kh|kl]
      drow[16 + o] = (bf16)(val - (float)hi);
    }
  }
}

// ===================== conv v (r20 v3, measured 53.5 µs): yF staged in LDS ==========
// Waves split o (16 each); yF staging = pure contiguous bf16 memcpy; afr 1/ks from L1;
// bfr 4/ks from LDS (bank-uniform 1KB rows). Load-early/write-late pipeline.
__global__ __launch_bounds__(256) void conv_v_kernel(
    const bf16* __restrict__ yF, const bf16* __restrict__ W3,
    const float* __restrict__ bias, bf16* __restrict__ VF) {
  __shared__ __align__(16) char smc[6 * YSLAB];   // [kh 3][half 2][wH 66][64B] linear
  const int t = threadIdx.x;
  const int lane = t & 63, wv = t >> 6;
  const int g = lane >> 4, ln = lane & 15;
  const int raw = blockIdx.x;          // 1024 = b(4) x h(64) x oh(4)
  const int b = raw >> 8;
  const int h = (raw >> 2) & 63;
  const int oh = raw & 3;
  const int obase = (oh << 6) + (wv << 4);   // wave owns 16 out-channels
  const int kh0 = (h == 0) ? 1 : 0, kh1 = (h == 63) ? 2 : 3;
  f32x4 acc[4];
#pragma unroll
  for (int wf = 0; wf < 4; ++wf) acc[wf] = (f32x4){0.f, 0.f, 0.f, 0.f};

  f32x4 xmain[6];
  f32x4 xtail[6];
#define YBASE(kh, half, chunk) ((const char*)yF + \
    (size_t)((((b * 64 + (h + (kh) - 1)) * 4 + (chunk)) * 2 + (half)) * YSLAB))

#define LOADC(chunk)                                                       \
  {                                                                        \
    _Pragma("unroll")                                                      \
    for (int kh = 0; kh < 3; ++kh)                                         \
      if (kh >= kh0 && kh < kh1)                                           \
        _Pragma("unroll")                                                  \
        for (int half = 0; half < 2; ++half) {                             \
          const char* src = YBASE(kh, half, chunk);                        \
          xmain[kh * 2 + half] = *(const f32x4*)(src + (t << 4));          \
          if (t < 8) xtail[kh * 2 + half] = *(const f32x4*)(src + 4096 + (t << 4)); \
        }                                                                  \
  }

#define WRITEC()                                                           \
  {                                                                        \
    _Pragma("unroll")                                                      \
    for (int kh = 0; kh < 3; ++kh)                                         \
      if (kh >= kh0 && kh < kh1)                                           \
        _Pragma("unroll")                                                  \
        for (int half = 0; half < 2; ++half) {                             \
          char* dst = smc + (kh * 2 + half) * YSLAB;                       \
          *(f32x4*)(dst + (t << 4)) = xmain[kh * 2 + half];                \
          if (t < 8) *(f32x4*)(dst + 4096 + (t << 4)) = xtail[kh * 2 + half]; \
        }                                                                  \
  }

  LOADC(0)
  WRITEC()
  __syncthreads();
  for (int chunk = 0; chunk < 4; ++chunk) {
    if (chunk < 3) LOADC(chunk + 1)
#pragma unroll
    for (int kh = 0; kh < 3; ++kh) {
      if (kh < kh0 || kh >= kh1) continue;
#pragma unroll
      for (int kw = 0; kw < 3; ++kw) {
#pragma unroll
        for (int half = 0; half < 2; ++half) {
          const int ks = ((kh * 3 + kw) << 1) + half;
          bf16x8 afr = *(const bf16x8*)&W3[(size_t)((chunk * 18 + ks) * 256 + obase + ln) * 32 + (g << 3)];
          const char* lrow = smc + (kh * 2 + half) * YSLAB + ((ln + kw) << 6) + (g << 4);
#pragma unroll
          for (int wf = 0; wf < 4; ++wf) {
            bf16x8 bfr = *(const bf16x8*)(lrow + (wf << 10));
            acc[wf] = mfma16(afr, bfr, acc[wf]);
          }
        }
      }
    }
    if (chunk < 3) {
      __syncthreads();
      WRITEC()
      __syncthreads();
    }
  }
#undef YBASE
#undef LOADC
#undef WRITEC
  const int cblk = obase >> 4;
#pragma unroll
  for (int r = 0; r < 4; ++r) {
    int c = obase + (g << 2) + r;
    int lnv = c & 15;
    float bvv = bias[c];
#pragma unroll
    for (int wf = 0; wf < 4; ++wf) {
      int p = (h << 6) + (wf << 4) + ln;
      int J = p >> 5, gv = (p >> 3) & 3, e = p & 7;
      VF[(((size_t)(((b << 7) + J) << 4) + cblk) << 9) + (gv << 7) + (lnv << 3) + e] =
          (bf16)(acc[wf][r] + bvv);
    }
  }
}

// ===================== attention =====================
// Proven structure (~45-55 µs): producer/consumer, __syncthreads dbuf,
// launch_bounds(512,2), VF fragment-ordered V -> 1KB coalesced av loads.
__global__ __launch_bounds__(512, 2) void attn_kernel(
    const bf16* __restrict__ qT, const bf16* __restrict__ kT,
    const bf16* __restrict__ VF, float* __restrict__ outp) {
  __shared__ __align__(16) char Klds[2 * 4096];   // [buf][row 64][64B] swizzled
  __shared__ __align__(16) char Plds[2 * 8192];   // [buf][f 4][ln 16][128B] swizzled
  __shared__ float lsumS[4][16];
  const int raw = blockIdx.x;          // 256
  const int b  = raw & 3;              // batch -> XCD pair {b, b+4}
  const int it = raw >> 2;             // 0..63
  const int i0 = it << 6;
  const int t = threadIdx.x;
  const int lane = t & 63, wv = t >> 6;
  const int g = lane >> 4, ln = lane & 15;
  const bool prod = (wv < 4);
  const int f = wv & 3;
  const int cb = f << 6;
  const int cblk0 = f << 2;

  const char* kTb = (const char*)kT + (((size_t)b << 12) << 6);
  const char* vfb = (const char*)VF + ((size_t)b << 21);

  bf16x8 bq1 = {}, bq2 = {};
  if (prod) {
    const bf16* qrow = &qT[(((size_t)b << 12) + i0 + (f << 4) + ln) * 64];
    bq1 = *(const bf16x8*)&qrow[g << 3];
    bq2 = *(const bf16x8*)&qrow[32 + (g << 3)];
  }
  float lsum = 0.f;
  const int krow = t >> 2, kc = t & 3;
  const uint32_t kwoff = ((uint32_t)krow << 6) + ((uint32_t)(kc ^ (krow & 3)) << 4);

  f32x4 acc[4][4];
#pragma unroll
  for (int cf = 0; cf < 4; ++cf)
#pragma unroll
    for (int ff = 0; ff < 4; ++ff) acc[cf][ff] = (f32x4){0.f, 0.f, 0.f, 0.f};
  bf16x8 avA[8], avB[8];

  if (prod)
    *(f32x4*)(Klds + kwoff) = *(const f32x4*)(kTb + ((size_t)krow << 6) + (kc << 4));
  __syncthreads();

  for (int m = 0; m < 32; ++m) {
    const int jtA = m << 1;
    if (prod) {
      f32x4 s[4];
#pragma unroll
      for (int jf = 0; jf < 4; ++jf) {
        const int row = (jf << 4) + ln;
        bf16x8 ak = *(const bf16x8*)(Klds + ((uint32_t)row << 6) + ((uint32_t)(g ^ (row & 3)) << 4));
        f32x4 z = {0.f, 0.f, 0.f, 0.f};
        s[jf] = mfma16(ak, bq2, mfma16(ak, bq1, z));
      }
#pragma unroll
      for (int jf = 0; jf < 4; ++jf) {
        union { bf16 h[4]; ull v; } pk;
#pragma unroll
        for (int r = 0; r < 4; ++r) {
          float pv = __builtin_amdgcn_exp2f(s[jf][r]);
          lsum += pv;
          pk.h[r] = (bf16)pv;
        }
        uint32_t bo = (((uint32_t)f << 11) + ((uint32_t)ln << 7) + (jf << 5) + (g << 3)) ^ ((ln & 7) << 4);
        *(ull*)(Plds + bo) = pk.v;
      }
      *(f32x4*)(Klds + 4096 + kwoff) =
          *(const f32x4*)(kTb + ((size_t)(((jtA + 1) << 6) + krow) << 6) + (kc << 4));
    } else {
#pragma unroll
      for (int ks = 0; ks < 2; ++ks)
#pragma unroll
        for (int cf = 0; cf < 4; ++cf)
          avB[ks * 4 + cf] = *(const bf16x8*)(vfb +
              ((size_t)(((jtA << 1) + ks) * 16 + cblk0 + cf) << 10) + (lane << 4));
      if (m > 0) {
        __builtin_amdgcn_s_setprio(1);
#pragma unroll
        for (int ks = 0; ks < 2; ++ks) {
          bf16x8 bp[4];
#pragma unroll
          for (int ff = 0; ff < 4; ++ff) {
            uint32_t bo = (8192u + ((uint32_t)ff << 11) + ((uint32_t)ln << 7) + (ks << 6) + (g << 4)) ^ ((ln & 7) << 4);
            bp[ff] = *(const bf16x8*)(Plds + bo);
          }
#pragma unroll
          for (int cf = 0; cf < 4; ++cf)
#pragma unroll
            for (int ff = 0; ff < 4; ++ff)
              acc[cf][ff] = mfma16(avA[ks * 4 + cf], bp[ff], acc[cf][ff]);
        }
        __builtin_amdgcn_s_setprio(0);
      }
    }
    __syncthreads();
    const int jtB = jtA + 1;
    if (prod) {
      f32x4 s[4];
#pragma unroll
      for (int jf = 0; jf < 4; ++jf) {
        const int row = (jf << 4) + ln;
        bf16x8 ak = *(const bf16x8*)(Klds + 4096 + ((uint32_t)row << 6) + ((uint32_t)(g ^ (row & 3)) << 4));
        f32x4 z = {0.f, 0.f, 0.f, 0.f};
        s[jf] = mfma16(ak, bq2, mfma16(ak, bq1, z));
      }
#pragma unroll
      for (int jf = 0; jf < 4; ++jf) {
        union { bf16 h[4]; ull v; } pk;
#pragma unroll
        for (int r = 0; r < 4; ++r) {
          float pv = __builtin_amdgcn_exp2f(s[jf][r]);
          lsum += pv;
          pk.h[r] = (bf16)pv;
        }
        uint32_t bo = (8192u + ((uint32_t)f << 11) + ((uint32_t)ln << 7) + (jf << 5) + (g << 3)) ^ ((ln & 7) << 4);
        *(ull*)(Plds + bo) = pk.v;
      }
      if (m < 31)
        *(f32x4*)(Klds + kwoff) =
            *(const f32x4*)(kTb + ((size_t)(((jtB + 1) << 6) + krow) << 6) + (kc << 4));
    } else {
#pragma unroll
      for (int ks = 0; ks < 2; ++ks)
#pragma unroll
        for (int cf = 0; cf < 4; ++cf)
          avA[ks * 4 + cf] = *(const bf16x8*)(vfb +
              ((size_t)(((jtB << 1) + ks) * 16 + cblk0 + cf) << 10) + (lane << 4));
      __builtin_amdgcn_s_setprio(1);
#pragma unroll
      for (int ks = 0; ks < 2; ++ks) {
        bf16x8 bp[4];
#pragma unroll
        for (int ff = 0; ff < 4; ++ff) {
          uint32_t bo = (((uint32_t)ff << 11) + ((uint32_t)ln << 7) + (ks << 6) + (g << 4)) ^ ((ln & 7) << 4);
          bp[ff] = *(const bf16x8*)(Plds + bo);
        }
#pragma unroll
        for (int cf = 0; cf < 4; ++cf)
#pragma unroll
          for (int ff = 0; ff < 4; ++ff)
            acc[cf][ff] = mfma16(avB[ks * 4 + cf], bp[ff], acc[cf][ff]);
      }
      __builtin_amdgcn_s_setprio(0);
    }
    __syncthreads();
  }
  if (prod) {
    float l = lsum;
    l += __shfl_xor(l, 16, 64);
    l += __shfl_xor(l, 32, 64);
    if (g == 0) lsumS[f][ln] = l;
  } else {
#pragma unroll
    for (int ks = 0; ks < 2; ++ks) {
      bf16x8 bp[4];
#pragma unroll
      for (int ff = 0; ff < 4; ++ff) {
        uint32_t bo = (8192u + ((uint32_t)ff << 11) + ((uint32_t)ln << 7) + (ks << 6) + (g << 4)) ^ ((ln & 7) << 4);
        bp[ff] = *(const bf16x8*)(Plds + bo);
      }
#pragma unroll
      for (int cf = 0; cf < 4; ++cf)
#pragma unroll
        for (int ff = 0; ff < 4; ++ff)
          acc[cf][ff] = mfma16(avA[ks * 4 + cf], bp[ff], acc[cf][ff]);
    }
  }
  __syncthreads();
  if (!prod) {
#pragma unroll
    for (int ff = 0; ff < 4; ++ff) {
      float rdiv = 1.f / lsumS[ff][ln];
      const int i = i0 + (ff << 4) + ln;
#pragma unroll
      for (int cf = 0; cf < 4; ++cf)
#pragma unroll
        for (int r = 0; r < 4; ++r) {
          int c = cb + (cf << 4) + (g << 2) + r;
          outp[(((size_t)b << 8) + c) * 4096 + i] = acc[cf][ff][r] * rdiv;
        }
    }
  }
}

// ===================== launch =====================
extern "C" void kernel_launch(void* const* d_in, const int* in_sizes, int n_in,
                              void* d_out, int out_size, void* d_ws, size_t ws_size,
                              hipStream_t stream) {
  const float* x  = (const float*)d_in[0];
  const float* y  = (const float*)d_in[1];
  const float* wq = (const float*)d_in[2];
  const float* bq = (const float*)d_in[3];
  const float* wk = (const float*)d_in[4];
  const float* bk = (const float*)d_in[5];
  const float* wv = (const float*)d_in[6];
  const float* bv = (const float*)d_in[7];
  float* out = (float*)d_out;

  char* ws = (char*)d_ws;
  bf16* qT  = (bf16*)(ws);
  bf16* kT  = (bf16*)(ws + (2u << 20));
  bf16* VF  = (bf16*)(ws + (3u << 20));
  bf16* W3v = (bf16*)(ws + (11u << 20));
  bf16* W3q = (bf16*)(ws + (11u << 20) + 1179648u);
  bf16* W3k = (bf16*)(ws + (11u << 20) + 1179648u + 73728u);
  bf16* yF  = (bf16*)(ws + (13u << 20));

  pack_all_kernel<<<2592, 256, 0, stream>>>(wv, wq, wk, W3v, W3q, W3k);
  conv_qk_kernel<<<512, 256, 0, stream>>>(x, y, W3q, W3k, bq, bk, qT, kT, yF);
  conv_v_kernel<<<1024, 256, 0, stream>>>(yF, W3v, bv, VF);
  attn_kernel<<<256, 512, 0, stream>>>(qT, kT, VF, out);
}

// Round 23
// 117.836 us; speedup vs baseline: 1.4350x; 1.0972x over previous
//
#include <hip/hip_runtime.h>
#include <stdint.h>

// B=4, C=256, H=W=64, N=4096, CQK=16, Ktot=C*9=2304
// ws layout:
//   qT  [4][4096][64] bf16   @ 0     (2 MiB)
//   kT  [4][4096][32] bf16   @ 2 MiB (1 MiB)
//   VF  [4][128][16][512] bf16 @ 3 MiB (8 MiB) V in MFMA-fragment order
//   W3v [4][18][256][32] bf16 @ 11 MiB (1152 KiB)
//   W3q [4][18][16][32]  bf16 @ +1179648 (72 KiB)
//   W3k [4][18][16][32]  bf16 @ +73728   (72 KiB)
//   yF  [4][64][4][2][66][32] bf16 @ 13 MiB (8.25 MiB)  y fragment-major; wH 0/65 zero halo
//        (written by conv_qk k-mode during its staging — pack_yF kernel eliminated)

typedef __bf16 bf16;
typedef bf16 bf16x8 __attribute__((ext_vector_type(8)));
typedef float f32x4 __attribute__((ext_vector_type(4)));
typedef unsigned long long ull;

#define DEV static __device__ __forceinline__

DEV f32x4 mfma16(bf16x8 a, bf16x8 b, f32x4 c) {
  return __builtin_amdgcn_mfma_f32_16x16x32_bf16(a, b, c, 0, 0, 0);
}

#define SMBUF 25344   // conv_qk staging buffer (3*66*64*2B)
#define YSLAB 4224    // one (kh,half) yF slab: 66 rows x 64B

// ===================== weight pack (all 3 tensors, one launch) =====================
__global__ void pack_all_kernel(const float* __restrict__ wv, const float* __restrict__ wq,
                                const float* __restrict__ wk, bf16* __restrict__ W3v,
                                bf16* __restrict__ W3q, bf16* __restrict__ W3k) {
  int idx = blockIdx.x * 256 + threadIdx.x;
  if (idx >= 663552) return;
  const float* src;
  bf16* dst;
  int rel, O;
  if (idx < 589824)      { src = wv; dst = W3v; rel = idx; O = 256; }
  else if (idx < 626688) { src = wq; dst = W3q; rel = idx - 589824; O = 16; }
  else                   { src = wk; dst = W3k; rel = idx - 626688; O = 16; }
  int o = rel / 2304, r = rel - o * 2304;
  int ci = r / 9, tap = r - ci * 9;
  int chunk = ci >> 6, c6 = ci & 63;
  int ks = (tap << 1) + (c6 >> 5), j = c6 & 31;
  dst[((chunk * 18 + ks) * O + o) * 32 + j] = (bf16)src[rel];
}

// ===================== conv staging (split load/write) ==========
DEV void stage_load(float4* xv, const float* __restrict__ img, int b, int h, int ci0, int t) {
  const int wg = t & 15, clq = t >> 4;
#pragma unroll
  for (int dh = 0; dh < 3; ++dh) {
    int hh = h + dh - 1;
    bool ok = (hh >= 0) && (hh < 64);
#pragma unroll
    for (int cc = 0; cc < 4; ++cc) {
      float4 v = make_float4(0.f, 0.f, 0.f, 0.f);
      if (ok) v = *(const float4*)&img[((((size_t)b << 8) + ci0 + (clq << 2) + cc) * 64 + hh) * 64 + (wg << 2)];
      xv[dh * 4 + cc] = v;
    }
  }
}

DEV void stage_write(char* smc, const float4* xv, int t) {
  if (t < 96) {
    int dh = t >> 5, r = t & 31;
    int wH = (r & 16) ? 65 : 0, cq = r & 15;
    *(ull*)(smc + ((((dh * 66 + wH) << 7) + (cq << 3)) ^ ((wH & 7) << 4))) = 0ull;
  }
  const int wg = t & 15, clq = t >> 4;
#pragma unroll
  for (int dh = 0; dh < 3; ++dh) {
    const float4 a = xv[dh * 4 + 0], b4 = xv[dh * 4 + 1], c4 = xv[dh * 4 + 2], d4 = xv[dh * 4 + 3];
    const float ax[4] = {a.x, a.y, a.z, a.w};
    const float bx[4] = {b4.x, b4.y, b4.z, b4.w};
    const float cx[4] = {c4.x, c4.y, c4.z, c4.w};
    const float dx[4] = {d4.x, d4.y, d4.z, d4.w};
#pragma unroll
    for (int q4 = 0; q4 < 4; ++q4) {
      int wH = (wg << 2) + q4 + 1;
      union { bf16 h4[4]; ull v; } pk;
      pk.h4[0] = (bf16)ax[q4]; pk.h4[1] = (bf16)bx[q4];
      pk.h4[2] = (bf16)cx[q4]; pk.h4[3] = (bf16)dx[q4];
      *(ull*)(smc + ((((dh * 66 + wH) << 7) + (clq << 3)) ^ ((wH & 7) << 4))) = pk.v;
    }
  }
}

// yF write from conv_qk k-mode registers (dh=1 row of xv), replaces pack_yF kernel.
DEV void yF_write(bf16* __restrict__ yFo, const float4* xv, int b, int h, int chunk, int t) {
  const int wg = t & 15, clq = t >> 4;
  const int half = clq >> 3, gr = clq & 7;
  ull* base = (ull*)yFo + ((size_t)(((b * 64 + h) * 4 + chunk) * 2 + half) * 66) * 8 + gr;
  const float4 a = xv[4 + 0], b4 = xv[4 + 1], c4 = xv[4 + 2], d4 = xv[4 + 3];
  const float ax[4] = {a.x, a.y, a.z, a.w};
  const float bx[4] = {b4.x, b4.y, b4.z, b4.w};
  const float cx[4] = {c4.x, c4.y, c4.z, c4.w};
  const float dx[4] = {d4.x, d4.y, d4.z, d4.w};
#pragma unroll
  for (int q4 = 0; q4 < 4; ++q4) {
    int wH = (wg << 2) + q4 + 1;
    union { bf16 h4[4]; ull v; } pk;
    pk.h4[0] = (bf16)ax[q4]; pk.h4[1] = (bf16)bx[q4];
    pk.h4[2] = (bf16)cx[q4]; pk.h4[3] = (bf16)dx[q4];
    base[(size_t)wH * 8] = pk.v;
  }
}

// ===================== conv q + k fused (O=16), pipelined staging; k-mode emits yF ====
__global__ __launch_bounds__(256) void conv_qk_kernel(
    const float* __restrict__ x, const float* __restrict__ y,
    const bf16* __restrict__ W3q, const bf16* __restrict__ W3k,
    const float* __restrict__ bq, const float* __restrict__ bk,
    bf16* __restrict__ qT, bf16* __restrict__ kT, bf16* __restrict__ yFo) {
  __shared__ __align__(16) char smc[2 * SMBUF];
  const int mode = blockIdx.x >> 8;       // 0=q, 1=k
  const float* img = mode ? y : x;
  const bf16* W3 = mode ? W3k : W3q;
  const float* bias = mode ? bk : bq;
  const int bi = blockIdx.x & 255;
  const int t = threadIdx.x;
  const int lane = t & 63, wv = t >> 6;
  const int g = lane >> 4, ln = lane & 15;
  const int b = bi >> 6;
  const int h = bi & 63;
  f32x4 acc = {0.f, 0.f, 0.f, 0.f};
  float4 xv[12];
  stage_load(xv, img, b, h, 0, t);
  if (mode) {
    if (t < 128) {
      int chunk = t >> 5, half = (t >> 4) & 1, wside = (t >> 3) & 1, gr = t & 7;
      int wH = wside ? 65 : 0;
      ((ull*)yFo)[((size_t)(((b * 64 + h) * 4 + chunk) * 2 + half) * 66 + wH) * 8 + gr] = 0ull;
    }
    yF_write(yFo, xv, b, h, 0, t);
  }
  stage_write(smc, xv, t);
  __syncthreads();
  for (int chunk = 0; chunk < 4; ++chunk) {
    char* cur = smc + (chunk & 1) * SMBUF;
    if (chunk < 3) {
      stage_load(xv, img, b, h, (chunk + 1) << 6, t);
      if (mode) yF_write(yFo, xv, b, h, chunk + 1, t);
    }
#pragma unroll
    for (int ks = 0; ks < 18; ++ks) {
      const int tap = ks >> 1, clb = (ks & 1) << 5;
      const int kh = tap / 3, kw = tap - kh * 3;
      const int wH = (wv << 4) + ln + kw;
      uint32_t bo = ((((kh * 66 + wH) << 6) + clb + (g << 3)) << 1) ^ ((wH & 7) << 4);
      bf16x8 bfr = *(const bf16x8*)(cur + bo);
      bf16x8 afr = *(const bf16x8*)&W3[(size_t)((chunk * 18 + ks) * 16 + ln) * 32 + (g << 3)];
      acc = mfma16(afr, bfr, acc);
    }
    if (chunk < 3) stage_write(smc + ((chunk + 1) & 1) * SMBUF, xv, t);
    __syncthreads();
  }
  const int p = (h << 6) + (wv << 4) + ln;
#pragma unroll
  for (int r = 0; r < 4; ++r) {
    int o = (g << 2) + r;
    float val = acc[r] + bias[o];
    if (mode == 0) {
      val *= 1.4426950408889634f;              // log2(e): softmax via exp2
      bf16* drow = qT + (((size_t)b << 12) + p) * 64;
      bf16 hi = (bf16)val;
      drow[o] = hi;
      drow[16 + o] = hi;                       // B1 = [qh|qh]
      drow[32 + o] = (bf16)(val - (float)hi);  // B2 = [ql|0]
      drow[48 + o] = (bf16)0.f;
    } else {
      bf16* drow = kT + (((size_t)b << 12) + p) * 32;
      bf16 hi = (bf16)val;
      drow[o] = hi;                            // A = [kh|kl]
      drow[16 + o] = (bf16)(val - (float)hi);
    }
  }
}

// ===================== conv v v3 + afr-hoist: 6-deep weight-load ILP ================
// r22 PMC: conv_v 95% stalled; chain = 1 afr L2/L1 load -> 4 dependent MFMAs, compiler
// keeps ~2 in flight (VGPR 96, 48 held by staging regs). Fix: load all 6 afr of a kh
// group up-front into a static array (48 VGPR; total ~150 << 512/wave needed for 4
// waves/SIMD) -> afr latency amortized 6x. Everything else identical to r22.
__global__ __launch_bounds__(256) void conv_v_kernel(
    const bf16* __restrict__ yF, const bf16* __restrict__ W3,
    const float* __restrict__ bias, bf16* __restrict__ VF) {
  __shared__ __align__(16) char smc[6 * YSLAB];   // [kh 3][half 2][wH 66][64B] linear
  const int t = threadIdx.x;
  const int lane = t & 63, wv = t >> 6;
  const int g = lane >> 4, ln = lane & 15;
  const int raw = blockIdx.x;          // 1024 = b(4) x h(64) x oh(4)
  const int b = raw >> 8;
  const int h = (raw >> 2) & 63;
  const int oh = raw & 3;
  const int obase = (oh << 6) + (wv << 4);   // wave owns 16 out-channels
  const int kh0 = (h == 0) ? 1 : 0, kh1 = (h == 63) ? 2 : 3;
  f32x4 acc[4];
#pragma unroll
  for (int wf = 0; wf < 4; ++wf) acc[wf] = (f32x4){0.f, 0.f, 0.f, 0.f};

  f32x4 xmain[6];
  f32x4 xtail[6];
#define YBASE(kh, half, chunk) ((const char*)yF + \
    (size_t)((((b * 64 + (h + (kh) - 1)) * 4 + (chunk)) * 2 + (half)) * YSLAB))

#define LOADC(chunk)                                                       \
  {                                                                        \
    _Pragma("unroll")                                                      \
    for (int kh = 0; kh < 3; ++kh)                                         \
      if (kh >= kh0 && kh < kh1)                                           \
        _Pragma("unroll")                                                  \
        for (int half = 0; half < 2; ++half) {                             \
          const char* src = YBASE(kh, half, chunk);                        \
          xmain[kh * 2 + half] = *(const f32x4*)(src + (t << 4));          \
          if (t < 8) xtail[kh * 2 + half] = *(const f32x4*)(src + 4096 + (t << 4)); \
        }                                                                  \
  }

#define WRITEC()                                                           \
  {                                                                        \
    _Pragma("unroll")                                                      \
    for (int kh = 0; kh < 3; ++kh)                                         \
      if (kh >= kh0 && kh < kh1)                                           \
        _Pragma("unroll")                                                  \
        for (int half = 0; half < 2; ++half) {                             \
          char* dst = smc + (kh * 2 + half) * YSLAB;                       \
          *(f32x4*)(dst + (t << 4)) = xmain[kh * 2 + half];                \
          if (t < 8) *(f32x4*)(dst + 4096 + (t << 4)) = xtail[kh * 2 + half]; \
        }                                                                  \
  }

  LOADC(0)
  WRITEC()
  __syncthreads();
  for (int chunk = 0; chunk < 4; ++chunk) {
    if (chunk < 3) LOADC(chunk + 1)
#pragma unroll
    for (int kh = 0; kh < 3; ++kh) {
      if (kh < kh0 || kh >= kh1) continue;
      // 6-deep afr prefetch: all (kw,half) weight fragments of this kh issue together
      bf16x8 afr[6];
#pragma unroll
      for (int i = 0; i < 6; ++i) {
        const int ks = kh * 6 + i;   // == ((kh*3+kw)<<1)+half with i = kw*2+half
        afr[i] = *(const bf16x8*)&W3[(size_t)((chunk * 18 + ks) * 256 + obase + ln) * 32 + (g << 3)];
      }
#pragma unroll
      for (int i = 0; i < 6; ++i) {
        const int kw = i >> 1, half = i & 1;
        const char* lrow = smc + (kh * 2 + half) * YSLAB + ((ln + kw) << 6) + (g << 4);
#pragma unroll
        for (int wf = 0; wf < 4; ++wf) {
          bf16x8 bfr = *(const bf16x8*)(lrow + (wf << 10));
          acc[wf] = mfma16(afr[i], bfr, acc[wf]);
        }
      }
    }
    if (chunk < 3) {
      __syncthreads();
      WRITEC()
      __syncthreads();
    }
  }
#undef YBASE
#undef LOADC
#undef WRITEC
  const int cblk = obase >> 4;
#pragma unroll
  for (int r = 0; r < 4; ++r) {
    int c = obase + (g << 2) + r;
    int lnv = c & 15;
    float bvv = bias[c];
#pragma unroll
    for (int wf = 0; wf < 4; ++wf) {
      int p = (h << 6) + (wf << 4) + ln;
      int J = p >> 5, gv = (p >> 3) & 3, e = p & 7;
      VF[(((size_t)(((b << 7) + J) << 4) + cblk) << 9) + (gv << 7) + (lnv << 3) + e] =
          (bf16)(acc[wf][r] + bvv);
    }
  }
}

// ===================== attention =====================
// Proven structure (~43-50 µs): producer/consumer, __syncthreads dbuf,
// launch_bounds(512,2), VF fragment-ordered V -> 1KB coalesced av loads.
__global__ __launch_bounds__(512, 2) void attn_kernel(
    const bf16* __restrict__ qT, const bf16* __restrict__ kT,
    const bf16* __restrict__ VF, float* __restrict__ outp) {
  __shared__ __align__(16) char Klds[2 * 4096];   // [buf][row 64][64B] swizzled
  __shared__ __align__(16) char Plds[2 * 8192];   // [buf][f 4][ln 16][128B] swizzled
  __shared__ float lsumS[4][16];
  const int raw = blockIdx.x;          // 256
  const int b  = raw & 3;              // batch -> XCD pair {b, b+4}
  const int it = raw >> 2;             // 0..63
  const int i0 = it << 6;
  const int t = threadIdx.x;
  const int lane = t & 63, wv = t >> 6;
  const int g = lane >> 4, ln = lane & 15;
  const bool prod = (wv < 4);
  const int f = wv & 3;
  const int cb = f << 6;
  const int cblk0 = f << 2;

  const char* kTb = (const char*)kT + (((size_t)b << 12) << 6);
  const char* vfb = (const char*)VF + ((size_t)b << 21);

  bf16x8 bq1 = {}, bq2 = {};
  if (prod) {
    const bf16* qrow = &qT[(((size_t)b << 12) + i0 + (f << 4) + ln) * 64];
    bq1 = *(const bf16x8*)&qrow[g << 3];
    bq2 = *(const bf16x8*)&qrow[32 + (g << 3)];
  }
  float lsum = 0.f;
  const int krow = t >> 2, kc = t & 3;
  const uint32_t kwoff = ((uint32_t)krow << 6) + ((uint32_t)(kc ^ (krow & 3)) << 4);

  f32x4 acc[4][4];
#pragma unroll
  for (int cf = 0; cf < 4; ++cf)
#pragma unroll
    for (int ff = 0; ff < 4; ++ff) acc[cf][ff] = (f32x4){0.f, 0.f, 0.f, 0.f};
  bf16x8 avA[8], avB[8];

  if (prod)
    *(f32x4*)(Klds + kwoff) = *(const f32x4*)(kTb + ((size_t)krow << 6) + (kc << 4));
  __syncthreads();

  for (int m = 0; m < 32; ++m) {
    const int jtA = m << 1;
    if (prod) {
      f32x4 s[4];
#pragma unroll
      for (int jf = 0; jf < 4; ++jf) {
        const int row = (jf << 4) + ln;
        bf16x8 ak = *(const bf16x8*)(Klds + ((uint32_t)row << 6) + ((uint32_t)(g ^ (row & 3)) << 4));
        f32x4 z = {0.f, 0.f, 0.f, 0.f};
        s[jf] = mfma16(ak, bq2, mfma16(ak, bq1, z));
      }
#pragma unroll
      for (int jf = 0; jf < 4; ++jf) {
        union { bf16 h[4]; ull v; } pk;
#pragma unroll
        for (int r = 0; r < 4; ++r) {
          float pv = __builtin_amdgcn_exp2f(s[jf][r]);
          lsum += pv;
          pk.h[r] = (bf16)pv;
        }
        uint32_t bo = (((uint32_t)f << 11) + ((uint32_t)ln << 7) + (jf << 5) + (g << 3)) ^ ((ln & 7) << 4);
        *(ull*)(Plds + bo) = pk.v;
      }
      *(f32x4*)(Klds + 4096 + kwoff) =
          *(const f32x4*)(kTb + ((size_t)(((jtA + 1) << 6) + krow) << 6) + (kc << 4));
    } else {
#pragma unroll
      for (int ks = 0; ks < 2; ++ks)
#pragma unroll
        for (int cf = 0; cf < 4; ++cf)
          avB[ks * 4 + cf] = *(const bf16x8*)(vfb +
              ((size_t)(((jtA << 1) + ks) * 16 + cblk0 + cf) << 10) + (lane << 4));
      if (m > 0) {
        __builtin_amdgcn_s_setprio(1);
#pragma unroll
        for (int ks = 0; ks < 2; ++ks) {
          bf16x8 bp[4];
#pragma unroll
          for (int ff = 0; ff < 4; ++ff) {
            uint32_t bo = (8192u + ((uint32_t)ff << 11) + ((uint32_t)ln << 7) + (ks << 6) + (g << 4)) ^ ((ln & 7) << 4);
            bp[ff] = *(const bf16x8*)(Plds + bo);
          }
#pragma unroll
          for (int cf = 0; cf < 4; ++cf)
#pragma unroll
            for (int ff = 0; ff < 4; ++ff)
              acc[cf][ff] = mfma16(avA[ks * 4 + cf], bp[ff], acc[cf][ff]);
        }
        __builtin_amdgcn_s_setprio(0);
      }
    }
    __syncthreads();
    const int jtB = jtA + 1;
    if (prod) {
      f32x4 s[4];
#pragma unroll
      for (int jf = 0; jf < 4; ++jf) {
        const int row = (jf << 4) + ln;
        bf16x8 ak = *(const bf16x8*)(Klds + 4096 + ((uint32_t)row << 6) + ((uint32_t)(g ^ (row & 3)) << 4));
        f32x4 z = {0.f, 0.f, 0.f, 0.f};
        s[jf] = mfma16(ak, bq2, mfma16(ak, bq1, z));
      }
#pragma unroll
      for (int jf = 0; jf < 4; ++jf) {
        union { bf16 h[4]; ull v; } pk;
#pragma unroll
        for (int r = 0; r < 4; ++r) {
          float pv = __builtin_amdgcn_exp2f(s[jf][r]);
          lsum += pv;
          pk.h[r] = (bf16)pv;
        }
        uint32_t bo = (8192u + ((uint32_t)f << 11) + ((uint32_t)ln << 7) + (jf << 5) + (g << 3)) ^ ((ln & 7) << 4);
        *(ull*)(Plds + bo) = pk.v;
      }
      if (m < 31)
        *(f32x4*)(Klds + kwoff) =
            *(const f32x4*)(kTb + ((size_t)(((jtB + 1) << 6) + krow) << 6) + (kc << 4));
    } else {
#pragma unroll
      for (int ks = 0; ks < 2; ++ks)
#pragma unroll
        for (int cf = 0; cf < 4; ++cf)
          avA[ks * 4 + cf] = *(const bf16x8*)(vfb +
              ((size_t)(((jtB << 1) + ks) * 16 + cblk0 + cf) << 10) + (lane << 4));
      __builtin_amdgcn_s_setprio(1);
#pragma unroll
      for (int ks = 0; ks < 2; ++ks) {
        bf16x8 bp[4];
#pragma unroll
        for (int ff = 0; ff < 4; ++ff) {
          uint32_t bo = (((uint32_t)ff << 11) + ((uint32_t)ln << 7) + (ks << 6) + (g << 4)) ^ ((ln & 7) << 4);
          bp[ff] = *(const bf16x8*)(Plds + bo);
        }
#pragma unroll
        for (int cf = 0; cf < 4; ++cf)
#pragma unroll
          for (int ff = 0; ff < 4; ++ff)
            acc[cf][ff] = mfma16(avB[ks * 4 + cf], bp[ff], acc[cf][ff]);
      }
      __builtin_amdgcn_s_setprio(0);
    }
    __syncthreads();
  }
  if (prod) {
    float l = lsum;
    l += __shfl_xor(l, 16, 64);
    l += __shfl_xor(l, 32, 64);
    if (g == 0) lsumS[f][ln] = l;
  } else {
#pragma unroll
    for (int ks = 0; ks < 2; ++ks) {
      bf16x8 bp[4];
#pragma unroll
      for (int ff = 0; ff < 4; ++ff) {
        uint32_t bo = (8192u + ((uint32_t)ff << 11) + ((uint32_t)ln << 7) + (ks << 6) + (g << 4)) ^ ((ln & 7) << 4);
        bp[ff] = *(const bf16x8*)(Plds + bo);
      }
#pragma unroll
      for (int cf = 0; cf < 4; ++cf)
#pragma unroll
        for (int ff = 0; ff < 4; ++ff)
          acc[cf][ff] = mfma16(avA[ks * 4 + cf], bp[ff], acc[cf][ff]);
    }
  }
  __syncthreads();
  if (!prod) {
#pragma unroll
    for (int ff = 0; ff < 4; ++ff) {
      float rdiv = 1.f / lsumS[ff][ln];
      const int i = i0 + (ff << 4) + ln;
#pragma unroll
      for (int cf = 0; cf < 4; ++cf)
#pragma unroll
        for (int r = 0; r < 4; ++r) {
          int c = cb + (cf << 4) + (g << 2) + r;
          outp[(((size_t)b << 8) + c) * 4096 + i] = acc[cf][ff][r] * rdiv;
        }
    }
  }
}

// ===================== launch =====================
extern "C" void kernel_launch(void* const* d_in, const int* in_sizes, int n_in,
                              void* d_out, int out_size, void* d_ws, size_t ws_size,
                              hipStream_t stream) {
  const float* x  = (const float*)d_in[0];
  const float* y  = (const float*)d_in[1];
  const float* wq = (const float*)d_in[2];
  const float* bq = (const float*)d_in[3];
  const float* wk = (const float*)d_in[4];
  const float* bk = (const float*)d_in[5];
  const float* wv = (const float*)d_in[6];
  const float* bv = (const float*)d_in[7];
  float* out = (float*)d_out;

  char* ws = (char*)d_ws;
  bf16* qT  = (bf16*)(ws);
  bf16* kT  = (bf16*)(ws + (2u << 20));
  bf16* VF  = (bf16*)(ws + (3u << 20));
  bf16* W3v = (bf16*)(ws + (11u << 20));
  bf16* W3q = (bf16*)(ws + (11u << 20) + 1179648u);
  bf16* W3k = (bf16*)(ws + (11u << 20) + 1179648u + 73728u);
  bf16* yF  = (bf16*)(ws + (13u << 20));

  pack_all_kernel<<<2592, 256, 0, stream>>>(wv, wq, wk, W3v, W3q, W3k);
  conv_qk_kernel<<<512, 256, 0, stream>>>(x, y, W3q, W3k, bq, bk, qT, kT, yF);
  conv_v_kernel<<<1024, 256, 0, stream>>>(yF, W3v, bv, VF);
  attn_kernel<<<256, 512, 0, stream>>>(qT, kT, VF, out);
}